// Round 4
// baseline (301.834 us; speedup 1.0000x reference)
//
#include <hip/hip_runtime.h>
#include <stdint.h>

#define NTOK 2048
#define DIM  1024
#define HID  2048
#define NEXP 8
#define CAP  4224   // 4096 assignments + 128 tile-overflow pad
#define RB   256    // router blocks

typedef __attribute__((ext_vector_type(8))) short short8;
typedef __attribute__((ext_vector_type(4))) float floatx4;
typedef __attribute__((ext_vector_type(4))) unsigned short ushortx4;
typedef __attribute__((ext_vector_type(4))) uint32_t uintx4;

static __device__ __forceinline__ unsigned short f2bf(float f) {
  uint32_t u = __builtin_bit_cast(uint32_t, f);
  u += 0x7fffu + ((u >> 16) & 1u);   // round-to-nearest-even
  return (unsigned short)(u >> 16);
}

// ---------------- router (fp32 exact, no atomics) ----------------
__global__ void __launch_bounds__(256) router_kernel(const float* __restrict__ x,
                                                     const float* __restrict__ Wr,
                                                     int* __restrict__ experts,
                                                     float* __restrict__ wts) {
  const int wave = threadIdx.x >> 6;
  const int lane = threadIdx.x & 63;

#pragma unroll
  for (int j = 0; j < 2; j++) {
    int t = blockIdx.x * 8 + wave * 2 + j;
    const float* xr = x + (size_t)t * DIM;
    float acc[NEXP];
#pragma unroll
    for (int e = 0; e < NEXP; e++) acc[e] = 0.f;
#pragma unroll
    for (int i = 0; i < 4; i++) {
      floatx4 v = ((const floatx4*)xr)[i * 64 + lane];
      int idx = (i * 64 + lane) * 4;
#pragma unroll
      for (int e = 0; e < NEXP; e++) {
        floatx4 w = *(const floatx4*)&Wr[e * DIM + idx];
        acc[e] += v.x * w.x + v.y * w.y + v.z * w.z + v.w * w.w;
      }
    }
#pragma unroll
    for (int e = 0; e < NEXP; e++) {
#pragma unroll
      for (int off = 32; off > 0; off >>= 1) acc[e] += __shfl_down(acc[e], off);
    }
    if (lane == 0) {
      float mx = acc[0];
      for (int e = 1; e < NEXP; e++) mx = fmaxf(mx, acc[e]);
      float p[NEXP], s = 0.f;
      for (int e = 0; e < NEXP; e++) { p[e] = expf(acc[e] - mx); s += p[e]; }
      float inv = 1.f / s;
      for (int e = 0; e < NEXP; e++) p[e] *= inv;
      int i0 = 0; float p0 = p[0];
      for (int e = 1; e < NEXP; e++) if (p[e] > p0) { p0 = p[e]; i0 = e; }   // ties: lowest idx
      int i1 = -1; float p1 = -1.f;
      for (int e = 0; e < NEXP; e++) if (e != i0 && p[e] > p1) { p1 = p[e]; i1 = e; }
      float rn = 1.f / (p0 + p1 + 1e-8f);
      experts[2 * t] = i0; experts[2 * t + 1] = i1;
      wts[2 * t] = p0 * rn; wts[2 * t + 1] = p1 * rn;
    }
  }
}

// ------- scanpos: counts + bases + per-assignment positions, one 64-lane wave.
__global__ void scanpos_kernel(const int* __restrict__ experts,
                               int* __restrict__ ctrl,
                               int* __restrict__ pos) {
  int lane = threadIdx.x;
  if (lane >= 64) return;
  int cnt[NEXP];
#pragma unroll
  for (int e = 0; e < NEXP; e++) cnt[e] = 0;
#pragma unroll 4
  for (int c = 0; c < 2 * NTOK / 64; c++) {
    int v = experts[c * 64 + lane];
#pragma unroll
    for (int e = 0; e < NEXP; e++) cnt[e] += __popcll(__ballot(v == e));
  }
  int basev[NEXP], s = 0;
#pragma unroll
  for (int e = 0; e < NEXP; e++) { basev[e] = s; s += cnt[e]; }
  if (lane < NEXP) { ctrl[lane] = cnt[lane]; ctrl[8 + lane] = basev[lane]; }
  int cur[NEXP];
#pragma unroll
  for (int e = 0; e < NEXP; e++) cur[e] = basev[e];
  unsigned long long below = (1ull << lane) - 1ull;
#pragma unroll 4
  for (int c = 0; c < 2 * NTOK / 64; c++) {
    int v = experts[c * 64 + lane];
    int p = 0;
#pragma unroll
    for (int e = 0; e < NEXP; e++) {
      unsigned long long m = __ballot(v == e);
      if (v == e) p = cur[e] + __popcll(m & below);
      cur[e] += __popcll(m);
    }
    pos[c * 64 + lane] = p;
  }
}

// ---------------- gather: compact token rows into Xe (bf16), no atomics ------
__global__ void __launch_bounds__(256) gather_kernel(const float* __restrict__ x,
                                                     const int* __restrict__ pos,
                                                     unsigned short* __restrict__ Xe) {
  int t = blockIdx.x;
  int p0 = pos[2 * t], p1 = pos[2 * t + 1];
  int i = threadIdx.x;
  floatx4 v = ((const floatx4*)(x + (size_t)t * DIM))[i];
  ushortx4 b;
  b.x = f2bf(v.x); b.y = f2bf(v.y); b.z = f2bf(v.z); b.w = f2bf(v.w);
  *(ushortx4*)(Xe + (size_t)p0 * DIM + 4 * i) = b;
  *(ushortx4*)(Xe + (size_t)p1 * DIM + 4 * i) = b;
}

// ---------------- 2-phase pipelined bf16 GEMM, fused fp32->bf16 B ------------
// A: bf16, staged via global_load_lds (round-0 fast path, XOR-swizzled source,
// linear dest). B: ORIGINAL fp32 weights, reg-staged: 8 float4 loads -> 16
// v_cvt_pk_bf16_f32 -> 4 ds_write_b128 into the SAME physical layout the gll
// path produces (slot l&7 of row holds global granule (l&7)^(row&7)), so the
// MFMA loop is byte-identical to round-0's (1x ds_read_b128 per fragment, no
// cvt, conflict-free).
// Pipeline per K-step (\u00a75.5 2-phase template): LOAD_B(t+1) -> STAGE_A(t+1) ->
// COMPUTE(t) -> WRITE_B(t+1) -> vmcnt(0) -> barrier. B latency hides under the
// 32 MFMAs via the rb data-dep (compiler emits vmcnt(4): A glls issued after);
// A's drain sits after compute. One barrier per K-step.
// C = A @ B^T.  EPI=0: relu(C)^2 -> bf16 (He).  EPI=1: fp32 store (Ye).
template <int K, int N, int EPI>
__global__ void __launch_bounds__(256) gemm_kernel(const unsigned short* __restrict__ A,
                                                   const float* __restrict__ B,
                                                   unsigned short* __restrict__ Cbf,
                                                   float* __restrict__ Cf,
                                                   const int* __restrict__ ctrl) {
  const int e = blockIdx.z;
  const int cnt = ctrl[e];
  const int m0 = blockIdx.y * 128;
  if (m0 >= cnt) return;
  const int base = ctrl[8 + e];
  const int n0 = blockIdx.x * 128;

  __shared__ __align__(16) unsigned short ldsA[2][128 * 64];  // 2 x 16 KB
  __shared__ __align__(16) unsigned short ldsB[2][128 * 64];  // 2 x 16 KB

  const int tid = threadIdx.x;
  const int lane = tid & 63;
  const int wave = tid >> 6;
  const int wm = wave & 1, wn = wave >> 1;

  const unsigned short* Ae = A + (size_t)(base + m0) * K;
  const float* Be = B + ((size_t)e * N + n0) * (size_t)K;

  const int rsub = lane >> 3;   // row within 8-row chunk
  const int sg = lane & 7;      // 16B-granule slot (bf16) within row

  floatx4 acc[4][4];
  floatx4 zero = {0.f, 0.f, 0.f, 0.f};
#pragma unroll
  for (int i = 0; i < 4; i++)
#pragma unroll
    for (int j = 0; j < 4; j++) acc[i][j] = zero;

  floatx4 rb0[4], rb1[4];   // B staging regs, live across COMPUTE

#define STAGE_A(k0, buf)                                                                        \
  _Pragma("unroll")                                                                             \
  for (int j = 0; j < 4; j++) {                                                                 \
    int c = wave * 4 + j;                                                                       \
    int rc = c * 8 + rsub;                                                                      \
    int g = sg ^ (rc & 7);                                                                      \
    const unsigned short* ga = Ae + (size_t)rc * K + (k0) + g * 8;                              \
    __builtin_amdgcn_global_load_lds((const __attribute__((address_space(1))) unsigned int*)ga, \
                                     (__attribute__((address_space(3))) unsigned int*)&ldsA[buf][c * 512], \
                                     16, 0, 0);                                                 \
  }

#define LOAD_B(k0)                                                                              \
  _Pragma("unroll")                                                                             \
  for (int j = 0; j < 4; j++) {                                                                 \
    int rc = (wave * 4 + j) * 8 + rsub;                                                         \
    int g = sg ^ (rc & 7);                                                                      \
    const float* gb = Be + (size_t)rc * K + (k0) + g * 8;                                       \
    rb0[j] = ((const floatx4*)gb)[0];                                                           \
    rb1[j] = ((const floatx4*)gb)[1];                                                           \
  }

#define WRITE_B(buf)                                                                            \
  _Pragma("unroll")                                                                             \
  for (int j = 0; j < 4; j++) {                                                                 \
    int c = wave * 4 + j;                                                                       \
    uintx4 uu;                                                                                  \
    asm("v_cvt_pk_bf16_f32 %0, %1, %2" : "=v"(uu.x) : "v"(rb0[j].x), "v"(rb0[j].y));            \
    asm("v_cvt_pk_bf16_f32 %0, %1, %2" : "=v"(uu.y) : "v"(rb0[j].z), "v"(rb0[j].w));            \
    asm("v_cvt_pk_bf16_f32 %0, %1, %2" : "=v"(uu.z) : "v"(rb1[j].x), "v"(rb1[j].y));            \
    asm("v_cvt_pk_bf16_f32 %0, %1, %2" : "=v"(uu.w) : "v"(rb1[j].z), "v"(rb1[j].w));            \
    *(short8*)&ldsB[buf][c * 512 + lane * 8] = __builtin_bit_cast(short8, uu);                  \
  }

#define COMPUTE(buf)                                                                            \
  _Pragma("unroll")                                                                             \
  for (int kk = 0; kk < 2; kk++) {                                                              \
    int gk = kk * 4 + (lane >> 4);                                                              \
    short8 af[4], bfr[4];                                                                       \
    _Pragma("unroll")                                                                           \
    for (int mi = 0; mi < 4; mi++) {                                                            \
      int row = wm * 64 + mi * 16 + (lane & 15);                                                \
      af[mi] = *(const short8*)&ldsA[buf][row * 64 + (gk ^ (row & 7)) * 8];                     \
    }                                                                                           \
    _Pragma("unroll")                                                                           \
    for (int ni = 0; ni < 4; ni++) {                                                            \
      int row = wn * 64 + ni * 16 + (lane & 15);                                                \
      bfr[ni] = *(const short8*)&ldsB[buf][row * 64 + (gk ^ (row & 7)) * 8];                    \
    }                                                                                           \
    _Pragma("unroll")                                                                           \
    for (int mi = 0; mi < 4; mi++)                                                              \
      _Pragma("unroll")                                                                         \
      for (int ni = 0; ni < 4; ni++)                                                            \
        acc[mi][ni] = __builtin_amdgcn_mfma_f32_16x16x32_bf16(af[mi], bfr[ni], acc[mi][ni], 0, 0, 0); \
  }

  constexpr int NT = K / 64;

  // prologue: tile 0 into buf 0
  LOAD_B(0)
  STAGE_A(0, 0)
  WRITE_B(0)                             // auto vmcnt(4) via rb data-dep
  __builtin_amdgcn_s_waitcnt(0x0f70);    // vmcnt(0): A gll drained
  __syncthreads();                       // ds_writes drained

  for (int t = 0; t < NT; ++t) {
    int cur = t & 1, nxt = cur ^ 1;
    if (t + 1 < NT) {
      LOAD_B((t + 1) * 64)               // B first: WRITE_B waits vmcnt(4), not 0
      STAGE_A((t + 1) * 64, nxt)
    }
    COMPUTE(cur)                         // 32 MFMA cover the in-flight loads
    if (t + 1 < NT) {
      WRITE_B(nxt)
      __builtin_amdgcn_s_waitcnt(0x0f70);
      __syncthreads();
    }
  }

  // epilogue: D row=(lane>>4)*4+reg, col=lane&15; mask stores past cnt.
  const int lm = lane >> 4;
  const int ln = lane & 15;
#pragma unroll
  for (int mi = 0; mi < 4; mi++) {
#pragma unroll
    for (int ni = 0; ni < 4; ni++) {
#pragma unroll
      for (int r = 0; r < 4; r++) {
        int row = m0 + wm * 64 + mi * 16 + lm * 4 + r;   // local row in expert segment
        if (row < cnt) {
          int col = n0 + wn * 64 + ni * 16 + ln;
          float v = acc[mi][ni][r];
          if (EPI == 0) {
            v = fmaxf(v, 0.f);
            v = v * v;
            Cbf[(size_t)(base + row) * N + col] = f2bf(v);
          } else {
            Cf[(size_t)(base + row) * N + col] = v;
          }
        }
      }
    }
  }
#undef STAGE_A
#undef LOAD_B
#undef WRITE_B
#undef COMPUTE
}

// ---------------- combine: out[t] = w0*Ye[p0] + w1*Ye[p1] --------------------
__global__ void __launch_bounds__(256) combine_kernel(const float* __restrict__ Ye,
                                                      const int* __restrict__ pos,
                                                      const float* __restrict__ wts,
                                                      float* __restrict__ out) {
  int t = blockIdx.x;
  int i = threadIdx.x;
  int p0 = pos[2 * t], p1 = pos[2 * t + 1];
  float w0 = wts[2 * t], w1 = wts[2 * t + 1];
  floatx4 y0 = ((const floatx4*)(Ye + (size_t)p0 * DIM))[i];
  floatx4 y1 = ((const floatx4*)(Ye + (size_t)p1 * DIM))[i];
  floatx4 o = y0 * w0 + y1 * w1;
  ((floatx4*)(out + (size_t)t * DIM))[i] = o;
  if (t == 0 && i == 0) out[(size_t)NTOK * DIM] = 0.f;  // aux_loss = 0
}

extern "C" void kernel_launch(void* const* d_in, const int* in_sizes, int n_in,
                              void* d_out, int out_size, void* d_ws, size_t ws_size,
                              hipStream_t stream) {
  const float* x   = (const float*)d_in[0];
  const float* Wr  = (const float*)d_in[1];
  const float* Wfc = (const float*)d_in[2];
  const float* Wpr = (const float*)d_in[3];
  float* out = (float*)d_out;
  char* ws = (char*)d_ws;

  int*   ctrl    = (int*)ws;                          // counts[8] bases[8]
  int*   experts = (int*)(ws + 128);                  // int2 per token
  int*   pos     = (int*)(ws + 128 + 16384);          // int2 per token
  float* wts     = (float*)(ws + 128 + 32768);        // float2 per token
  unsigned short* Xe = (unsigned short*)(ws + 65536); // [CAP x DIM] bf16
  unsigned short* He = Xe + (size_t)CAP * DIM;        // [CAP x HID] bf16
  float*          Ye = (float*)(He + (size_t)CAP * HID);  // [CAP x DIM] f32

  router_kernel<<<RB, 256, 0, stream>>>(x, Wr, experts, wts);
  scanpos_kernel<<<1, 64, 0, stream>>>(experts, ctrl, pos);
  gather_kernel<<<NTOK, 256, 0, stream>>>(x, pos, Xe);

  gemm_kernel<DIM, HID, 0><<<dim3(HID / 128, 16, NEXP), 256, 0, stream>>>(Xe, Wfc, He, nullptr, ctrl);
  gemm_kernel<HID, DIM, 1><<<dim3(DIM / 128, 16, NEXP), 256, 0, stream>>>(He, Wpr, nullptr, Ye, ctrl);

  combine_kernel<<<NTOK, 256, 0, stream>>>(Ye, pos, wts, out);
}